// Round 4
// baseline (491.430 us; speedup 1.0000x reference)
//
#include <hip/hip_runtime.h>
#include <hip/hip_bf16.h>

// Problem: B=4096, N=64, FIN=256, D1=512, D2=128.
// Inputs fp32; action_mask int32; OUTPUT fp32 (reference returns float32 —
// harness reads d_out as float32; the "(bf16,...)" in the test label is
// literal text about the comparison mode, not the output dtype).
// Value head (W3,b3,W4,b4) is dead code.
// fp32 -> bf16 at staging; GEMMs on bf16 MFMA; fp32 epilogue + store.

typedef unsigned short u16;
typedef __bf16 bf16x8 __attribute__((ext_vector_type(8)));
typedef float f32x4 __attribute__((ext_vector_type(4)));

#define FIN 256
#define D1  512
#define D2  128
#define NNA 64
#define NEGV -10000000.0f

__device__ __forceinline__ float bf2f(u16 u) {
  unsigned int i = ((unsigned int)u) << 16;
  return __builtin_bit_cast(float, i);
}
__device__ __forceinline__ u16 f2bf(float f) {
  unsigned int i = __builtin_bit_cast(unsigned int, f);
  return (u16)((i + 0x7FFFu + ((i >> 16) & 1u)) >> 16);
}
__device__ __forceinline__ bf16x8 ld_frag_g(const u16* p) {   // 16B bf16 fragment
  return __builtin_bit_cast(bf16x8, *(const uint4*)p);
}
// load 8 consecutive fp32, convert to bf16x8 fragment
__device__ __forceinline__ bf16x8 ld_frag_f32(const float* p) {
  float4 a = *(const float4*)p, b = *(const float4*)(p + 4);
  u16 s[8];
  s[0] = f2bf(a.x); s[1] = f2bf(a.y); s[2] = f2bf(a.z); s[3] = f2bf(a.w);
  s[4] = f2bf(b.x); s[5] = f2bf(b.y); s[6] = f2bf(b.z); s[7] = f2bf(b.w);
  return __builtin_bit_cast(bf16x8, *(uint4*)s);
}

// ---------------------------------------------------------------------------
// k_prep: W1 [256,512], W2 [1024,128] fp32 -> bf16 MFMA B-fragment order:
// Wp[kt][nt][lane][j] = W[kt*32 + (lane>>4)*8 + j][nt*16 + (lane&15)]
// ---------------------------------------------------------------------------
__global__ __launch_bounds__(256) void k_prep(const float* __restrict__ W1,
                                              const float* __restrict__ W2,
                                              u16* __restrict__ W1p,
                                              u16* __restrict__ W2p) {
  int tid = blockIdx.x * 256 + threadIdx.x;
  if (tid < 131072) {
    int idx = tid;
    int j = idx & 7, lane = (idx >> 3) & 63, nt = (idx >> 9) & 31, kt = idx >> 14;
    int k = kt * 32 + (lane >> 4) * 8 + j;
    int n = nt * 16 + (lane & 15);
    W1p[idx] = f2bf(W1[k * D1 + n]);
  } else {
    int idx = tid - 131072;     // idx < 32768
    int j = idx & 7, lane = (idx >> 3) & 63, nt = (idx >> 9) & 7, kt = idx >> 12;
    int k = kt * 32 + (lane >> 4) * 8 + j;
    int n = nt * 16 + (lane & 15);
    W2p[idx] = f2bf(W2[k * D2 + n]);
  }
}

// ---------------------------------------------------------------------------
// k_x: X = obs_x @ W1 + b1 -> bf16, left half of outw [4096,1024].
// Grid (32,4), 256 thr = 4 waves; wave: 32 rows x 128 cols, K=256.
// ---------------------------------------------------------------------------
__global__ __launch_bounds__(256) void k_x(const float* __restrict__ obs,
                                           const u16* __restrict__ W1p,
                                           const float* __restrict__ pb1,
                                           u16* __restrict__ outw) {
  const int w = threadIdx.x >> 6, lane = threadIdx.x & 63;
  const int q = lane >> 4, c0 = lane & 15;
  const int m0 = blockIdx.x * 128 + w * 32;
  const int ntg0 = blockIdx.y * 8;

  f32x4 acc[2][8];
#pragma unroll
  for (int a = 0; a < 2; ++a)
#pragma unroll
    for (int c = 0; c < 8; ++c) acc[a][c] = (f32x4){0.f, 0.f, 0.f, 0.f};

#pragma unroll 1
  for (int kt = 0; kt < 8; ++kt) {
    bf16x8 afr[2], bfr[8];
#pragma unroll
    for (int mt = 0; mt < 2; ++mt)
      afr[mt] = ld_frag_f32(obs + (m0 + mt * 16 + c0) * FIN + kt * 32 + q * 8);
#pragma unroll
    for (int nt = 0; nt < 8; ++nt)
      bfr[nt] = ld_frag_g(W1p + ((kt * 32 + ntg0 + nt) * 64 + lane) * 8);
#pragma unroll
    for (int mt = 0; mt < 2; ++mt)
#pragma unroll
      for (int nt = 0; nt < 8; ++nt)
        acc[mt][nt] = __builtin_amdgcn_mfma_f32_16x16x32_bf16(afr[mt], bfr[nt], acc[mt][nt], 0, 0, 0);
  }

#pragma unroll
  for (int nt = 0; nt < 8; ++nt) {
    const int n = (ntg0 + nt) * 16 + c0;
    const float bias = pb1[n];
#pragma unroll
    for (int mt = 0; mt < 2; ++mt)
#pragma unroll
      for (int i = 0; i < 4; ++i) {
        const int row = m0 + mt * 16 + q * 4 + i;
        outw[row * 1024 + n] = f2bf(acc[mt][nt][i] + bias);
      }
  }
}

// ---------------------------------------------------------------------------
// k_attn: one block (512 thr = 8 waves) per batch b:
//   stage others_b [64,256] fp32->bf16 LDS (stride 264), y = others_b@W1+b1
//   via MFMA (wave w: 64 rows x 64 cols), y -> LDS (stride 520, aliases A),
//   alpha = x.y/sqrt(512), softmax(64), c = beta.y -> right half of outw.
// ---------------------------------------------------------------------------
__global__ __launch_bounds__(512, 4) void k_attn(const float* __restrict__ others,
                                                 const u16* __restrict__ W1p,
                                                 const float* __restrict__ pb1,
                                                 u16* __restrict__ outw) {
  __shared__ __align__(16) u16 s_y[64 * 520];   // y tile; first 33.8KB alias A tile
  __shared__ __align__(16) u16 s_x[512];
  __shared__ float s_alpha[64];
  __shared__ float s_beta[64];
  u16* s_a = s_y;                                // A tile bf16, stride 264

  const int tid = threadIdx.x;
  const int bidx = blockIdx.x;

  {
    const float* src = others + bidx * (NNA * FIN);
#pragma unroll
    for (int i = 0; i < 4; ++i) {
      int idx = i * 512 + tid;          // 8-elem chunk index
      int p = idx * 8;
      int row = p >> 8, col = p & 255;
      bf16x8 v = ld_frag_f32(src + p);
      *(uint4*)(s_a + row * 264 + col) = __builtin_bit_cast(uint4, v);
    }
    if (tid < 64) ((uint4*)s_x)[tid] = ((const uint4*)(outw + bidx * 1024))[tid];
  }
  __syncthreads();

  const int w = tid >> 6, lane = tid & 63, q = lane >> 4, c0 = lane & 15;

  f32x4 acc[4][4];
#pragma unroll
  for (int a = 0; a < 4; ++a)
#pragma unroll
    for (int c = 0; c < 4; ++c) acc[a][c] = (f32x4){0.f, 0.f, 0.f, 0.f};

#pragma unroll 1
  for (int kt = 0; kt < 8; ++kt) {
    bf16x8 afr[4], bfr[4];
#pragma unroll
    for (int mt = 0; mt < 4; ++mt)
      afr[mt] = __builtin_bit_cast(bf16x8,
                  *(const uint4*)(s_a + (mt * 16 + c0) * 264 + kt * 32 + q * 8));
#pragma unroll
    for (int nt = 0; nt < 4; ++nt)
      bfr[nt] = ld_frag_g(W1p + ((kt * 32 + w * 4 + nt) * 64 + lane) * 8);
#pragma unroll
    for (int mt = 0; mt < 4; ++mt)
#pragma unroll
      for (int nt = 0; nt < 4; ++nt)
        acc[mt][nt] = __builtin_amdgcn_mfma_f32_16x16x32_bf16(afr[mt], bfr[nt], acc[mt][nt], 0, 0, 0);
  }
  __syncthreads();   // done reading s_a; safe to overwrite with y

#pragma unroll
  for (int nt = 0; nt < 4; ++nt) {
    const int n = w * 64 + nt * 16 + c0;
    const float bias = pb1[n];
#pragma unroll
    for (int mt = 0; mt < 4; ++mt)
#pragma unroll
      for (int i = 0; i < 4; ++i)
        s_y[(mt * 16 + q * 4 + i) * 520 + n] = f2bf(acc[mt][nt][i] + bias);
  }
  __syncthreads();

  // alpha[m] = x . y[m] / sqrt(512); 8 threads per row m
  {
    const int m = tid >> 3, j = tid & 7;
    const u16* yr = s_y + m * 520;
    float s = 0.f;
#pragma unroll 4
    for (int it = 0; it < 64; ++it) {
      int d = j + it * 8;
      s += bf2f(s_x[d]) * bf2f(yr[d]);
    }
    s += __shfl_xor(s, 1); s += __shfl_xor(s, 2); s += __shfl_xor(s, 4);
    if (j == 0) s_alpha[m] = s * 0.04419417382415922f;  // 1/sqrt(512)
  }
  __syncthreads();

  if (tid < 64) {   // wave 0: softmax over the 64 agents
    float v = s_alpha[tid];
    float mx = v;
#pragma unroll
    for (int off = 1; off < 64; off <<= 1) mx = fmaxf(mx, __shfl_xor(mx, off));
    float e = __expf(v - mx);
    float se = e;
#pragma unroll
    for (int off = 1; off < 64; off <<= 1) se += __shfl_xor(se, off);
    s_beta[tid] = e / se;
  }
  __syncthreads();

  {
    float s = 0.f;
#pragma unroll 4
    for (int m = 0; m < 64; ++m)
      s += s_beta[m] * bf2f(s_y[m * 520 + tid]);
    outw[bidx * 1024 + 512 + tid] = f2bf(s);
  }
}

// ---------------------------------------------------------------------------
// k_head: logits = softmax(out @ W2 + b2); masked += NEG -> d_out FP32.
// Grid 32, 256 thr = 4 waves; wave: 32 rows x 128 cols, K=1024.
// Row softmax in-register (row's 128 cols on one 16-lane group x 8 regs).
// ---------------------------------------------------------------------------
__global__ __launch_bounds__(256) void k_head(const u16* __restrict__ outw,
                                              const u16* __restrict__ W2p,
                                              const float* __restrict__ pb2,
                                              const int* __restrict__ mask,
                                              float* __restrict__ out) {
  const int w = threadIdx.x >> 6, lane = threadIdx.x & 63;
  const int q = lane >> 4, c0 = lane & 15;
  const int m0 = blockIdx.x * 128 + w * 32;

  f32x4 acc[2][8];
#pragma unroll
  for (int a = 0; a < 2; ++a)
#pragma unroll
    for (int c = 0; c < 8; ++c) acc[a][c] = (f32x4){0.f, 0.f, 0.f, 0.f};

#pragma unroll 1
  for (int kt = 0; kt < 32; ++kt) {
    bf16x8 afr[2], bfr[8];
#pragma unroll
    for (int mt = 0; mt < 2; ++mt)
      afr[mt] = ld_frag_g(outw + (m0 + mt * 16 + c0) * 1024 + kt * 32 + q * 8);
#pragma unroll
    for (int nt = 0; nt < 8; ++nt)
      bfr[nt] = ld_frag_g(W2p + ((kt * 8 + nt) * 64 + lane) * 8);
#pragma unroll
    for (int mt = 0; mt < 2; ++mt)
#pragma unroll
      for (int nt = 0; nt < 8; ++nt)
        acc[mt][nt] = __builtin_amdgcn_mfma_f32_16x16x32_bf16(afr[mt], bfr[nt], acc[mt][nt], 0, 0, 0);
  }

  float b2f[8];
#pragma unroll
  for (int nt = 0; nt < 8; ++nt) b2f[nt] = pb2[nt * 16 + c0];

#pragma unroll
  for (int mt = 0; mt < 2; ++mt) {
#pragma unroll
    for (int i = 0; i < 4; ++i) {
      const int row = m0 + mt * 16 + q * 4 + i;
      float v[8];
      float mx = -3.0e38f;
#pragma unroll
      for (int nt = 0; nt < 8; ++nt) { v[nt] = acc[mt][nt][i] + b2f[nt]; mx = fmaxf(mx, v[nt]); }
      mx = fmaxf(mx, __shfl_xor(mx, 1)); mx = fmaxf(mx, __shfl_xor(mx, 2));
      mx = fmaxf(mx, __shfl_xor(mx, 4)); mx = fmaxf(mx, __shfl_xor(mx, 8));
      float se = 0.f;
#pragma unroll
      for (int nt = 0; nt < 8; ++nt) { v[nt] = __expf(v[nt] - mx); se += v[nt]; }
      se += __shfl_xor(se, 1); se += __shfl_xor(se, 2);
      se += __shfl_xor(se, 4); se += __shfl_xor(se, 8);
      const float inv = 1.f / se;
#pragma unroll
      for (int nt = 0; nt < 8; ++nt) {
        const int col = nt * 16 + c0;
        float p = fminf(fmaxf(v[nt] * inv, 0.f), 1.f);   // NaN-safe clamp to [0,1]
        float o = mask[row * D2 + col] ? p : (p + NEGV); // fp32, like the reference
        out[row * D2 + col] = o;
      }
    }
  }
}

extern "C" void kernel_launch(void* const* d_in, const int* in_sizes, int n_in,
                              void* d_out, int out_size, void* d_ws, size_t ws_size,
                              hipStream_t stream) {
  const float* obs = (const float*)d_in[0];   // [4096,256] fp32
  const float* oth = (const float*)d_in[1];   // [4096,64,256] fp32
  const int*   msk = (const int*)d_in[2];     // [4096,128] int32
  const float* W1  = (const float*)d_in[3];   // [256,512] fp32
  const float* b1  = (const float*)d_in[4];   // [512] fp32
  const float* W2  = (const float*)d_in[5];   // [1024,128] fp32
  const float* b2  = (const float*)d_in[6];   // [128] fp32
  // d_in[7..10] = W3,b3,W4,b4: dead code (value head deleted in reference)
  float* out = (float*)d_out;                 // [4096,128] fp32

  char* ws = (char*)d_ws;
  u16* W1p  = (u16*)ws;                    // 262144 B
  u16* W2p  = (u16*)(ws + 262144);         //  65536 B (pad to 262144)
  u16* outw = (u16*)(ws + 524288);         // [4096,1024] bf16 = 8 MB

  k_prep<<<640, 256, 0, stream>>>(W1, W2, W1p, W2p);
  k_x<<<dim3(32, 4), 256, 0, stream>>>(obs, W1p, b1, outw);
  k_attn<<<4096, 512, 0, stream>>>(oth, W1p, b1, outw);
  k_head<<<32, 256, 0, stream>>>(outw, W2p, b2, msk, out);
}